// Round 1
// 633.561 us; speedup vs baseline: 1.0629x; 1.0629x over previous
//
#include <hip/hip_runtime.h>
#include <stdint.h>

typedef unsigned short u16;
typedef __bf16 bf16x8 __attribute__((ext_vector_type(8)));
typedef float f32x4 __attribute__((ext_vector_type(4)));
typedef u16 u16x4 __attribute__((ext_vector_type(4)));
typedef u16 u16x8 __attribute__((ext_vector_type(8)));

__device__ __forceinline__ u16 f2b(float f) {  // fp32 -> bf16 bits, RNE
    unsigned u = __builtin_bit_cast(unsigned, f);
    u = u + 0x7FFFu + ((u >> 16) & 1u);
    return (u16)(u >> 16);
}
__device__ __forceinline__ float b2f(u16 b) {
    return __builtin_bit_cast(float, (unsigned)b << 16);
}

// async global->LDS, 16B per lane. LDS dest = wave-uniform base + lane*16.
__device__ __forceinline__ void glds16(const u16* g, u16* l) {
    __builtin_amdgcn_global_load_lds(
        (const __attribute__((address_space(1))) void*)g,
        (__attribute__((address_space(3))) void*)l,
        16, 0, 0);
}

template <int N> __device__ __forceinline__ void waitvm() {
    if constexpr (N == 0)      asm volatile("s_waitcnt vmcnt(0)" ::: "memory");
    else if constexpr (N == 3) asm volatile("s_waitcnt vmcnt(3)" ::: "memory");
    else if constexpr (N == 4) asm volatile("s_waitcnt vmcnt(4)" ::: "memory");
    else if constexpr (N == 6) asm volatile("s_waitcnt vmcnt(6)" ::: "memory");
    else if constexpr (N == 8) asm volatile("s_waitcnt vmcnt(8)" ::: "memory");
}

// ---------------------------------------------------------------- cast fp32->bf16
__global__ __launch_bounds__(256) void cast_bf16(const float* __restrict__ src,
                                                 u16* __restrict__ dst, int n) {
    int i = (blockIdx.x * 256 + threadIdx.x) * 4;
    if (i >= n) return;
    f32x4 v = *(const f32x4*)(src + i);
    u16x4 o;
    o.x = f2b(v.x); o.y = f2b(v.y); o.z = f2b(v.z); o.w = f2b(v.w);
    *(u16x4*)(dst + i) = o;
}

// ---------------------------------------------------------------- GEMM C = A * Bt^T  (legacy 128x128)
// Kept for the small v_t GEMM (M=512) where the big-tile kernel can't fill the grid.
template <int OUT_BF16>
__global__ __launch_bounds__(256) void gemm_bt(const u16* __restrict__ A,
                                               const u16* __restrict__ Bt,
                                               void* __restrict__ Cout,
                                               int M, int N, int K) {
    __shared__ u16 As[128 * 32];
    __shared__ u16 Bs[128 * 32];
    const int tid  = threadIdx.x;
    const int w    = tid >> 6;
    const int lane = tid & 63;
    const int quad = lane >> 4;
    const int ml   = lane & 15;
    const long bm  = (long)blockIdx.y * 128;
    const long bn  = (long)blockIdx.x * 128;
    const int wm   = (w >> 1) * 64;
    const int wn   = (w & 1) * 64;
    const int grow = lane >> 2;
    const int gcol = (lane & 3) * 8;

    const u16* Ag = A  + (bm + w * 16 + grow) * (long)K + gcol;
    const u16* Bg = Bt + (bn + w * 16 + grow) * (long)K + gcol;
    u16* lAs0 = &As[(w * 16) * 32];
    u16* lAs1 = &As[(64 + w * 16) * 32];
    u16* lBs0 = &Bs[(w * 16) * 32];
    u16* lBs1 = &Bs[(64 + w * 16) * 32];

    const f32x4 fz = {0.f, 0.f, 0.f, 0.f};
    f32x4 acc[4][4];
#pragma unroll
    for (int i = 0; i < 4; ++i)
#pragma unroll
        for (int j = 0; j < 4; ++j) acc[i][j] = fz;

    for (int k0 = 0; k0 < K; k0 += 32) {
        __syncthreads();
        glds16(Ag + k0,                lAs0);
        glds16(Ag + 64 * (long)K + k0, lAs1);
        glds16(Bg + k0,                lBs0);
        glds16(Bg + 64 * (long)K + k0, lBs1);
        __builtin_amdgcn_s_waitcnt(0);
        __syncthreads();
        bf16x8 af[4], bfr[4];
#pragma unroll
        for (int mt = 0; mt < 4; ++mt)
            af[mt] = *(const bf16x8*)&As[(wm + mt * 16 + ml) * 32 + quad * 8];
#pragma unroll
        for (int nt = 0; nt < 4; ++nt)
            bfr[nt] = *(const bf16x8*)&Bs[(wn + nt * 16 + ml) * 32 + quad * 8];
#pragma unroll
        for (int mt = 0; mt < 4; ++mt)
#pragma unroll
            for (int nt = 0; nt < 4; ++nt)
                acc[mt][nt] = __builtin_amdgcn_mfma_f32_16x16x32_bf16(
                    af[mt], bfr[nt], acc[mt][nt], 0, 0, 0);
    }
#pragma unroll
    for (int mt = 0; mt < 4; ++mt)
#pragma unroll
        for (int nt = 0; nt < 4; ++nt)
#pragma unroll
            for (int r = 0; r < 4; ++r) {
                long row = bm + wm + mt * 16 + quad * 4 + r;
                long col = bn + wn + nt * 16 + ml;
                float v = acc[mt][nt][r];
                if (OUT_BF16) ((u16*)Cout)[row * N + col] = f2b(v);
                else          ((float*)Cout)[row * N + col] = v;
            }
}

// ---------------------------------------------------------------- GEMM 256-wide tile, counted-vmcnt pipeline
// C = A * Bt^T. A: MxK bf16 rm; Bt: NxK bf16 rm. BM=256, BN in {256,128}, BK=32.
// 512 threads = 8 waves (2M x 4N). 4-buffer LDS ring, 3-tile prefetch lead via
// global_load_lds; ONE raw s_barrier per K-tile; steady-state vmcnt(2*LPT) -- never 0.
// LDS XOR swizzle (chunk ^= (row>>1)&3) applied on the global SOURCE address
// (linear LDS dest, rule #21) and on the ds_read address -> bank-uniform reads.
// Requires: M%256==0, N%BN==0, K%32==0, K/32>=3.
template <int OUT_BF16, int BN>
__global__ __launch_bounds__(512, 2) void gemm256(const u16* __restrict__ A,
                                                  const u16* __restrict__ Bt,
                                                  void* __restrict__ Cout,
                                                  int M, int N, int K, int nbx) {
    (void)M;
    constexpr int NFRAG = BN / 64;            // 4 or 2 n-fragments per wave
    constexpr int ASZ = 256 * 32;             // u16 elems per A buffer
    constexpr int BSZ = BN * 32;
    constexpr int LPT = (BN == 256) ? 4 : 3;  // glds instructions per K-tile
    __shared__ u16 sm[4][ASZ + BSZ];          // 128 KiB (BN=256) / 96 KiB (BN=128)

    const int tid  = threadIdx.x;
    const int w    = tid >> 6;
    const int lane = tid & 63;
    const int quad = lane >> 4;
    const int ml   = lane & 15;
    const int wm   = (w >> 2) * 128;          // wave row base within 256
    const int wn   = (w & 3) * (BN / 4);      // wave col base within BN

    // T1: bijective XCD swizzle (m204)
    const int nwg = gridDim.x;
    const int q8 = nwg >> 3, r8 = nwg & 7;
    const int xcd = blockIdx.x & 7, loc = blockIdx.x >> 3;
    const int wg  = (xcd < r8 ? xcd * (q8 + 1) : r8 * (q8 + 1) + (xcd - r8) * q8) + loc;
    const long bm = (long)(wg / nbx) * 256;
    const long bn = (long)(wg % nbx) * BN;

    // staging: per issue 512 threads x 16B = 8 KiB = 128 rows x 64B.
    // LDS chunk (row, cc') holds global chunk cc = cc' ^ ((row>>1)&3).
    const int  srow = w * 16 + (lane >> 2);              // 0..127
    const int  scc  = (lane & 3) ^ ((lane >> 3) & 3);    // pre-swizzled source chunk
    const u16* Ag0  = A  + (bm + srow) * (long)K + scc * 8;
    const u16* Ag1  = Ag0 + 128 * (long)K;
    const u16* Bg0  = Bt + (bn + srow) * (long)K + scc * 8;
    const u16* Bg1  = (BN == 256) ? Bg0 + 128 * (long)K : Bg0;
    const int  ldsw = w * 512;                           // wave-uniform dest (u16 elems)

    // compute-side swizzled read chunk (row&7 == ml&7 for all frags)
    const int ccr  = quad ^ ((ml >> 1) & 3);
    const int aoff = (wm + ml) * 32 + ccr * 8;           // + mt*512
    const int boff = (wn + ml) * 32 + ccr * 8;           // + nt*512

    const f32x4 fz = {0.f, 0.f, 0.f, 0.f};
    f32x4 acc[8][NFRAG];
#pragma unroll
    for (int i = 0; i < 8; ++i)
#pragma unroll
        for (int j = 0; j < NFRAG; ++j) acc[i][j] = fz;

    const int NT = K >> 5;

#define STAGE(tt)                                                      \
    {                                                                  \
        u16* base = &sm[(tt) & 3][0];                                  \
        const long ko = (long)(tt) * 32;                               \
        glds16(Ag0 + ko, base + ldsw);                                 \
        glds16(Ag1 + ko, base + 4096 + ldsw);                          \
        glds16(Bg0 + ko, base + ASZ + ldsw);                           \
        if (BN == 256) glds16(Bg1 + ko, base + ASZ + 4096 + ldsw);     \
    }

    STAGE(0); STAGE(1); STAGE(2);

    for (int t = 0; t < NT; ++t) {
        // tile t landed iff all but the newest (issued-after-t) loads are done
        if (t < NT - 2)       waitvm<2 * LPT>();
        else if (t == NT - 2) waitvm<LPT>();
        else                  waitvm<0>();
        __builtin_amdgcn_s_barrier();          // raw barrier: no vmcnt drain
        __builtin_amdgcn_sched_barrier(0);
        if (t + 3 < NT) STAGE(t + 3);          // ring slot (t+3)&3 == (t-1)&3: reads done

        const u16* Ab = &sm[t & 3][0];
        const u16* Bb = Ab + ASZ;
        bf16x8 af[8];
#pragma unroll
        for (int mt = 0; mt < 8; ++mt)
            af[mt] = *(const bf16x8*)(Ab + aoff + mt * 512);
#pragma unroll
        for (int nh = 0; nh < NFRAG / 2; ++nh) {
            bf16x8 b0 = *(const bf16x8*)(Bb + boff + (2 * nh + 0) * 512);
            bf16x8 b1 = *(const bf16x8*)(Bb + boff + (2 * nh + 1) * 512);
            __builtin_amdgcn_s_setprio(1);
#pragma unroll
            for (int mt = 0; mt < 8; ++mt) {
                acc[mt][2 * nh]     = __builtin_amdgcn_mfma_f32_16x16x32_bf16(
                    af[mt], b0, acc[mt][2 * nh], 0, 0, 0);
                acc[mt][2 * nh + 1] = __builtin_amdgcn_mfma_f32_16x16x32_bf16(
                    af[mt], b1, acc[mt][2 * nh + 1], 0, 0, 0);
            }
            __builtin_amdgcn_s_setprio(0);
        }
    }
#undef STAGE

#pragma unroll
    for (int mt = 0; mt < 8; ++mt)
#pragma unroll
        for (int nt = 0; nt < NFRAG; ++nt)
#pragma unroll
            for (int r = 0; r < 4; ++r) {
                long row = bm + wm + mt * 16 + quad * 4 + r;
                long col = bn + wn + nt * 16 + ml;
                float v = acc[mt][nt][r];
                if (OUT_BF16) ((u16*)Cout)[row * N + col] = f2b(v);
                else          ((float*)Cout)[row * N + col] = v;
            }
}

// ---------------------------------------------------------------- RMSNorm + RoPE + relayout
__global__ __launch_bounds__(64) void norm_rope(const u16* __restrict__ qgk,
                                                const float* __restrict__ cosp,
                                                const float* __restrict__ sinp,
                                                const float* __restrict__ qw,
                                                const float* __restrict__ kw,
                                                u16* __restrict__ qf,
                                                u16* __restrict__ kf) {
    const int t = blockIdx.x;
    const int u = blockIdx.y;
    const int lane = threadIdx.x;
    const int b = t >> 11, s = t & 2047;
    const u16* src; const float* wgt; u16* dst;
    if (u < 16) {
        src = qgk + (long)t * 8704 + u * 512;
        wgt = qw;
        dst = qf + ((long)(b * 16 + u) * 2048 + s) * 256;
    } else {
        int kh = u - 16;
        src = qgk + (long)t * 8704 + 8192 + kh * 256;
        wgt = kw;
        dst = kf + ((long)(b * 2 + kh) * 2048 + s) * 256;
    }
    const int d0 = lane * 4;
    u16x4 raw = *(const u16x4*)(src + d0);
    float x0 = b2f(raw.x), x1 = b2f(raw.y), x2 = b2f(raw.z), x3 = b2f(raw.w);
    float ss = x0 * x0 + x1 * x1 + x2 * x2 + x3 * x3;
    for (int off = 32; off; off >>= 1) ss += __shfl_xor(ss, off, 64);
    float inv = rsqrtf(ss * (1.0f / 256.0f) + 1e-6f);
    float n0 = x0 * inv * wgt[d0 + 0];
    float n1 = x1 * inv * wgt[d0 + 1];
    float n2 = x2 * inv * wgt[d0 + 2];
    float n3 = x3 * inv * wgt[d0 + 3];
    float p0 = __shfl_xor(n0, 8, 64);
    float p1 = __shfl_xor(n1, 8, 64);
    float p2 = __shfl_xor(n2, 8, 64);
    float p3 = __shfl_xor(n3, 8, 64);
    if (lane < 16) {
        f32x4 c  = *(const f32x4*)(cosp + (long)t * 64 + d0);
        f32x4 sn = *(const f32x4*)(sinp + (long)t * 64 + d0);
        float sgn = (lane < 8) ? -1.f : 1.f;
        n0 = n0 * c[0] + sgn * p0 * sn[0];
        n1 = n1 * c[1] + sgn * p1 * sn[1];
        n2 = n2 * c[2] + sgn * p2 * sn[2];
        n3 = n3 * c[3] + sgn * p3 * sn[3];
    }
    const float qs = (u < 16) ? 0.0625f : 1.0f;
    n0 *= qs; n1 *= qs; n2 *= qs; n3 *= qs;
    u16x4 o;
    o.x = f2b(n0); o.y = f2b(n1); o.z = f2b(n2); o.w = f2b(n3);
    *(u16x4*)(dst + d0) = o;
}

// ---------------------------------------------------------------- flash attention + gate
__global__ __launch_bounds__(256, 2) void attn_fused(const u16* __restrict__ qf,
                                                     const u16* __restrict__ kf,
                                                     const u16* __restrict__ vt,
                                                     const u16* __restrict__ qgk,
                                                     u16* __restrict__ attn_g) {
    __shared__ u16 Ks[64 * 264];
    __shared__ u16 Vt[256 * 72];
    __shared__ u16 P[64 * 72];
    const int flat = blockIdx.x;
    const int qt = 31 - (flat >> 5);
    const int h  = flat & 15;
    const int b  = (flat >> 4) & 1;
    const int kh = h >> 3;
    const int tid = threadIdx.x;
    const int w = tid >> 6, lane = tid & 63;
    const int quad = lane >> 4, ml = lane & 15;
    const int qbase = qt * 64;
    const int qrow = qbase + w * 16;

    const u16* qptr = qf + ((long)(b * 16 + h) * 2048 + qrow + ml) * 256;
    bf16x8 qfrag[8];
#pragma unroll
    for (int dd = 0; dd < 8; ++dd)
        qfrag[dd] = *(const bf16x8*)(qptr + dd * 32 + quad * 8);

    const f32x4 fz = {0.f, 0.f, 0.f, 0.f};
    f32x4 oacc[16];
#pragma unroll
    for (int i = 0; i < 16; ++i) oacc[i] = fz;
    float lsum[4] = {0.f, 0.f, 0.f, 0.f};

    const u16* kbp = kf + (long)(b * 2 + kh) * 2048 * 256;
    const long vbase = (long)kh * 256 * 4096 + (long)b * 2048;

    u16x8 Kreg[8], Vreg[8];
#pragma unroll
    for (int i = 0; i < 8; ++i) {
        int c = i * 256 + tid;
        Kreg[i] = *(const u16x8*)(kbp + (long)(c >> 5) * 256 + (c & 31) * 8);
        Vreg[i] = *(const u16x8*)(vt + vbase + (long)(c >> 3) * 4096 + (c & 7) * 8);
    }

    const int nkt = qt + 1;
    for (int kt = 0; kt < nkt; ++kt) {
        __syncthreads();
#pragma unroll
        for (int i = 0; i < 8; ++i) {
            int c = i * 256 + tid;
            *(u16x8*)&Ks[(c >> 5) * 264 + (c & 31) * 8] = Kreg[i];
            *(u16x8*)&Vt[(c >> 3) * 72 + (c & 7) * 8]   = Vreg[i];
        }
        __syncthreads();
        if (kt + 1 < nkt) {
            const int kb2 = (kt + 1) * 64;
#pragma unroll
            for (int i = 0; i < 8; ++i) {
                int c = i * 256 + tid;
                Kreg[i] = *(const u16x8*)(kbp + (long)(kb2 + (c >> 5)) * 256 + (c & 31) * 8);
                Vreg[i] = *(const u16x8*)(vt + vbase + (long)(c >> 3) * 4096 + kb2 + (c & 7) * 8);
            }
        }

        f32x4 sacc[4];
#pragma unroll
        for (int i = 0; i < 4; ++i) sacc[i] = fz;
#pragma unroll
        for (int dd = 0; dd < 8; ++dd) {
            bf16x8 kf0 = *(const bf16x8*)&Ks[(0 * 16 + ml) * 264 + dd * 32 + quad * 8];
            bf16x8 kf1 = *(const bf16x8*)&Ks[(1 * 16 + ml) * 264 + dd * 32 + quad * 8];
            bf16x8 kf2 = *(const bf16x8*)&Ks[(2 * 16 + ml) * 264 + dd * 32 + quad * 8];
            bf16x8 kf3 = *(const bf16x8*)&Ks[(3 * 16 + ml) * 264 + dd * 32 + quad * 8];
            sacc[0] = __builtin_amdgcn_mfma_f32_16x16x32_bf16(qfrag[dd], kf0, sacc[0], 0, 0, 0);
            sacc[1] = __builtin_amdgcn_mfma_f32_16x16x32_bf16(qfrag[dd], kf1, sacc[1], 0, 0, 0);
            sacc[2] = __builtin_amdgcn_mfma_f32_16x16x32_bf16(qfrag[dd], kf2, sacc[2], 0, 0, 0);
            sacc[3] = __builtin_amdgcn_mfma_f32_16x16x32_bf16(qfrag[dd], kf3, sacc[3], 0, 0, 0);
        }

        const bool diag = (kt == qt);
#pragma unroll
        for (int nt = 0; nt < 4; ++nt)
#pragma unroll
            for (int r = 0; r < 4; ++r) {
                float sv = sacc[nt][r];
                if (diag) {
                    int col = nt * 16 + ml;
                    int row = w * 16 + quad * 4 + r;
                    sv = (col > row) ? -1e30f : sv;
                }
                float pv = __expf(sv - 16.0f);
                lsum[r] += pv;
                P[(w * 16 + quad * 4 + r) * 72 + nt * 16 + ml] = f2b(pv);
            }

#pragma unroll
        for (int ks = 0; ks < 2; ++ks) {
            bf16x8 pfrag = *(const bf16x8*)&P[(w * 16 + ml) * 72 + ks * 32 + quad * 8];
#pragma unroll
            for (int dt = 0; dt < 16; ++dt) {
                bf16x8 vfrag = *(const bf16x8*)&Vt[(dt * 16 + ml) * 72 + ks * 32 + quad * 8];
                oacc[dt] = __builtin_amdgcn_mfma_f32_16x16x32_bf16(pfrag, vfrag, oacc[dt], 0, 0, 0);
            }
        }
    }

#pragma unroll
    for (int off = 1; off < 16; off <<= 1)
#pragma unroll
        for (int r = 0; r < 4; ++r) lsum[r] += __shfl_xor(lsum[r], off, 64);

#pragma unroll
    for (int dt = 0; dt < 16; ++dt)
#pragma unroll
        for (int r = 0; r < 4; ++r) {
            int srow = qrow + quad * 4 + r;
            long tok = (long)b * 2048 + srow;
            int d = dt * 16 + ml;
            float o = oacc[dt][r] / lsum[r];
            float g = b2f(qgk[tok * 8704 + h * 512 + 256 + d]);
            float gv = o / (1.f + __expf(-g));
            attn_g[tok * 4096 + h * 256 + d] = f2b(gv);
        }
}

// ---------------------------------------------------------------- launch
extern "C" void kernel_launch(void* const* d_in, const int* in_sizes, int n_in,
                              void* d_out, int out_size, void* d_ws, size_t ws_size,
                              hipStream_t stream) {
    (void)in_sizes; (void)n_in; (void)out_size;
    const float* hidden = (const float*)d_in[0];
    const float* cosp   = (const float*)d_in[1];
    const float* sinp   = (const float*)d_in[2];
    const float* Wq     = (const float*)d_in[3];
    const float* Wk     = (const float*)d_in[4];
    const float* Wv     = (const float*)d_in[5];
    const float* Wo     = (const float*)d_in[6];
    const float* qw     = (const float*)d_in[7];
    const float* kw     = (const float*)d_in[8];
    float* out = (float*)d_out;

    char* p = (char*)d_ws;
    u16* h_bf   = (u16*)p; p += (size_t)8388608 * 2;   // hidden bf16 (4096x2048)
    u16* Wqk_bf = (u16*)p; p += (size_t)17825792 * 2;  // Wq||Wk (8704x2048)
    u16* Wv_bf  = (u16*)p; p += (size_t)1048576 * 2;   // Wv (512x2048)
    u16* Wo_bf  = (u16*)p; p += (size_t)8388608 * 2;   // Wo (2048x4096)
    u16* qgk    = (u16*)p; p += (size_t)35651584 * 2;  // (4096x8704)
    u16* v_t    = (u16*)p; p += (size_t)2097152 * 2;   // V^T (512x4096)
    u16* q_f    = (u16*)p; p += (size_t)16777216 * 2;  // (2,16,2048,256)
    u16* k_f    = (u16*)p; p += (size_t)2097152 * 2;   // (2,2,2048,256)
    u16* attn_g = (u16*)p; p += (size_t)16777216 * 2;  // (4096x4096)
    if ((size_t)(p - (char*)d_ws) > ws_size) return;

    cast_bf16<<<8192,  256, 0, stream>>>(hidden, h_bf, 8388608);
    cast_bf16<<<16384, 256, 0, stream>>>(Wq, Wqk_bf, 16777216);
    cast_bf16<<<1024,  256, 0, stream>>>(Wk, Wqk_bf + (size_t)8192 * 2048, 1048576);
    cast_bf16<<<1024,  256, 0, stream>>>(Wv, Wv_bf, 1048576);
    cast_bf16<<<8192,  256, 0, stream>>>(Wo, Wo_bf, 8388608);

    // qgk = hidden @ [Wq;Wk]^T   (4096 x 8704)  -- 256-tile pipelined GEMM
    gemm256<1, 256><<<dim3(544), 512, 0, stream>>>(h_bf, Wqk_bf, qgk, 4096, 8704, 2048, 34);
    // v_t = Wv @ hidden^T        (512 x 4096)   -- small M: legacy kernel
    gemm_bt<1><<<dim3(32, 4), 256, 0, stream>>>(Wv_bf, h_bf, v_t, 512, 4096, 2048);

    norm_rope<<<dim3(4096, 18), 64, 0, stream>>>(qgk, cosp, sinp, qw, kw, q_f, k_f);

    attn_fused<<<dim3(1024), 256, 0, stream>>>(q_f, k_f, v_t, qgk, attn_g);

    // out = attn_g @ Wo^T        (4096 x 2048) fp32 -- BN=128 fills 256 CUs
    gemm256<0, 128><<<dim3(256), 512, 0, stream>>>(attn_g, Wo_bf, out, 4096, 2048, 4096, 16);
}

// Round 3
// 596.471 us; speedup vs baseline: 1.1290x; 1.0622x over previous
//
#include <hip/hip_runtime.h>
#include <stdint.h>

typedef unsigned short u16;
typedef __bf16 bf16x8 __attribute__((ext_vector_type(8)));
typedef float f32x4 __attribute__((ext_vector_type(4)));
typedef u16 u16x4 __attribute__((ext_vector_type(4)));
typedef u16 u16x8 __attribute__((ext_vector_type(8)));

__device__ __forceinline__ u16 f2b(float f) {  // fp32 -> bf16 bits, RNE
    unsigned u = __builtin_bit_cast(unsigned, f);
    u = u + 0x7FFFu + ((u >> 16) & 1u);
    return (u16)(u >> 16);
}
__device__ __forceinline__ float b2f(u16 b) {
    return __builtin_bit_cast(float, (unsigned)b << 16);
}

// async global->LDS, 16B per lane. LDS dest = wave-uniform base + lane*16.
__device__ __forceinline__ void glds16(const u16* g, u16* l) {
    __builtin_amdgcn_global_load_lds(
        (const __attribute__((address_space(1))) void*)g,
        (__attribute__((address_space(3))) void*)l,
        16, 0, 0);
}

template <int N> __device__ __forceinline__ void waitvm() {
    if constexpr (N == 0)      asm volatile("s_waitcnt vmcnt(0)" ::: "memory");
    else if constexpr (N == 3) asm volatile("s_waitcnt vmcnt(3)" ::: "memory");
    else if constexpr (N == 4) asm volatile("s_waitcnt vmcnt(4)" ::: "memory");
    else if constexpr (N == 6) asm volatile("s_waitcnt vmcnt(6)" ::: "memory");
    else if constexpr (N == 8) asm volatile("s_waitcnt vmcnt(8)" ::: "memory");
}

// ---------------------------------------------------------------- cast fp32->bf16
__global__ __launch_bounds__(256) void cast_bf16(const float* __restrict__ src,
                                                 u16* __restrict__ dst, int n) {
    int i = (blockIdx.x * 256 + threadIdx.x) * 4;
    if (i >= n) return;
    f32x4 v = *(const f32x4*)(src + i);
    u16x4 o;
    o.x = f2b(v.x); o.y = f2b(v.y); o.z = f2b(v.z); o.w = f2b(v.w);
    *(u16x4*)(dst + i) = o;
}

// ---------------------------------------------------------------- GEMM C = A * Bt^T  (legacy 128x128)
// Kept for the small v_t GEMM (M=512) where the big-tile kernel can't fill the grid.
template <int OUT_BF16>
__global__ __launch_bounds__(256) void gemm_bt(const u16* __restrict__ A,
                                               const u16* __restrict__ Bt,
                                               void* __restrict__ Cout,
                                               int M, int N, int K) {
    __shared__ u16 As[128 * 32];
    __shared__ u16 Bs[128 * 32];
    const int tid  = threadIdx.x;
    const int w    = tid >> 6;
    const int lane = tid & 63;
    const int quad = lane >> 4;
    const int ml   = lane & 15;
    const long bm  = (long)blockIdx.y * 128;
    const long bn  = (long)blockIdx.x * 128;
    const int wm   = (w >> 1) * 64;
    const int wn   = (w & 1) * 64;
    const int grow = lane >> 2;
    const int gcol = (lane & 3) * 8;

    const u16* Ag = A  + (bm + w * 16 + grow) * (long)K + gcol;
    const u16* Bg = Bt + (bn + w * 16 + grow) * (long)K + gcol;
    u16* lAs0 = &As[(w * 16) * 32];
    u16* lAs1 = &As[(64 + w * 16) * 32];
    u16* lBs0 = &Bs[(w * 16) * 32];
    u16* lBs1 = &Bs[(64 + w * 16) * 32];

    const f32x4 fz = {0.f, 0.f, 0.f, 0.f};
    f32x4 acc[4][4];
#pragma unroll
    for (int i = 0; i < 4; ++i)
#pragma unroll
        for (int j = 0; j < 4; ++j) acc[i][j] = fz;

    for (int k0 = 0; k0 < K; k0 += 32) {
        __syncthreads();
        glds16(Ag + k0,                lAs0);
        glds16(Ag + 64 * (long)K + k0, lAs1);
        glds16(Bg + k0,                lBs0);
        glds16(Bg + 64 * (long)K + k0, lBs1);
        __builtin_amdgcn_s_waitcnt(0);
        __syncthreads();
        bf16x8 af[4], bfr[4];
#pragma unroll
        for (int mt = 0; mt < 4; ++mt)
            af[mt] = *(const bf16x8*)&As[(wm + mt * 16 + ml) * 32 + quad * 8];
#pragma unroll
        for (int nt = 0; nt < 4; ++nt)
            bfr[nt] = *(const bf16x8*)&Bs[(wn + nt * 16 + ml) * 32 + quad * 8];
#pragma unroll
        for (int mt = 0; mt < 4; ++mt)
#pragma unroll
            for (int nt = 0; nt < 4; ++nt)
                acc[mt][nt] = __builtin_amdgcn_mfma_f32_16x16x32_bf16(
                    af[mt], bfr[nt], acc[mt][nt], 0, 0, 0);
    }
#pragma unroll
    for (int mt = 0; mt < 4; ++mt)
#pragma unroll
        for (int nt = 0; nt < 4; ++nt)
#pragma unroll
            for (int r = 0; r < 4; ++r) {
                long row = bm + wm + mt * 16 + quad * 4 + r;
                long col = bn + wn + nt * 16 + ml;
                float v = acc[mt][nt][r];
                if (OUT_BF16) ((u16*)Cout)[row * N + col] = f2b(v);
                else          ((float*)Cout)[row * N + col] = v;
            }
}

// ---------------------------------------------------------------- GEMM 256-wide tile, counted-vmcnt pipeline
template <int OUT_BF16, int BN>
__global__ __launch_bounds__(512, 2) void gemm256(const u16* __restrict__ A,
                                                  const u16* __restrict__ Bt,
                                                  void* __restrict__ Cout,
                                                  int M, int N, int K, int nbx) {
    (void)M;
    constexpr int NFRAG = BN / 64;
    constexpr int ASZ = 256 * 32;
    constexpr int BSZ = BN * 32;
    constexpr int LPT = (BN == 256) ? 4 : 3;
    __shared__ u16 sm[4][ASZ + BSZ];

    const int tid  = threadIdx.x;
    const int w    = tid >> 6;
    const int lane = tid & 63;
    const int quad = lane >> 4;
    const int ml   = lane & 15;
    const int wm   = (w >> 2) * 128;
    const int wn   = (w & 3) * (BN / 4);

    const int nwg = gridDim.x;
    const int q8 = nwg >> 3, r8 = nwg & 7;
    const int xcd = blockIdx.x & 7, loc = blockIdx.x >> 3;
    const int wg  = (xcd < r8 ? xcd * (q8 + 1) : r8 * (q8 + 1) + (xcd - r8) * q8) + loc;
    const long bm = (long)(wg / nbx) * 256;
    const long bn = (long)(wg % nbx) * BN;

    const int  srow = w * 16 + (lane >> 2);
    const int  scc  = (lane & 3) ^ ((lane >> 3) & 3);
    const u16* Ag0  = A  + (bm + srow) * (long)K + scc * 8;
    const u16* Ag1  = Ag0 + 128 * (long)K;
    const u16* Bg0  = Bt + (bn + srow) * (long)K + scc * 8;
    const u16* Bg1  = (BN == 256) ? Bg0 + 128 * (long)K : Bg0;
    const int  ldsw = w * 512;

    const int ccr  = quad ^ ((ml >> 1) & 3);
    const int aoff = (wm + ml) * 32 + ccr * 8;
    const int boff = (wn + ml) * 32 + ccr * 8;

    const f32x4 fz = {0.f, 0.f, 0.f, 0.f};
    f32x4 acc[8][NFRAG];
#pragma unroll
    for (int i = 0; i < 8; ++i)
#pragma unroll
        for (int j = 0; j < NFRAG; ++j) acc[i][j] = fz;

    const int NT = K >> 5;

#define STAGE(tt)                                                      \
    {                                                                  \
        u16* base = &sm[(tt) & 3][0];                                  \
        const long ko = (long)(tt) * 32;                               \
        glds16(Ag0 + ko, base + ldsw);                                 \
        glds16(Ag1 + ko, base + 4096 + ldsw);                          \
        glds16(Bg0 + ko, base + ASZ + ldsw);                           \
        if (BN == 256) glds16(Bg1 + ko, base + ASZ + 4096 + ldsw);     \
    }

    STAGE(0); STAGE(1); STAGE(2);

    for (int t = 0; t < NT; ++t) {
        if (t < NT - 2)       waitvm<2 * LPT>();
        else if (t == NT - 2) waitvm<LPT>();
        else                  waitvm<0>();
        __builtin_amdgcn_s_barrier();
        __builtin_amdgcn_sched_barrier(0);
        if (t + 3 < NT) STAGE(t + 3);

        const u16* Ab = &sm[t & 3][0];
        const u16* Bb = Ab + ASZ;
        bf16x8 af[8];
#pragma unroll
        for (int mt = 0; mt < 8; ++mt)
            af[mt] = *(const bf16x8*)(Ab + aoff + mt * 512);
#pragma unroll
        for (int nh = 0; nh < NFRAG / 2; ++nh) {
            bf16x8 b0 = *(const bf16x8*)(Bb + boff + (2 * nh + 0) * 512);
            bf16x8 b1 = *(const bf16x8*)(Bb + boff + (2 * nh + 1) * 512);
            __builtin_amdgcn_s_setprio(1);
#pragma unroll
            for (int mt = 0; mt < 8; ++mt) {
                acc[mt][2 * nh]     = __builtin_amdgcn_mfma_f32_16x16x32_bf16(
                    af[mt], b0, acc[mt][2 * nh], 0, 0, 0);
                acc[mt][2 * nh + 1] = __builtin_amdgcn_mfma_f32_16x16x32_bf16(
                    af[mt], b1, acc[mt][2 * nh + 1], 0, 0, 0);
            }
            __builtin_amdgcn_s_setprio(0);
        }
    }
#undef STAGE

#pragma unroll
    for (int mt = 0; mt < 8; ++mt)
#pragma unroll
        for (int nt = 0; nt < NFRAG; ++nt)
#pragma unroll
            for (int r = 0; r < 4; ++r) {
                long row = bm + wm + mt * 16 + quad * 4 + r;
                long col = bn + wn + nt * 16 + ml;
                float v = acc[mt][nt][r];
                if (OUT_BF16) ((u16*)Cout)[row * N + col] = f2b(v);
                else          ((float*)Cout)[row * N + col] = v;
            }
}

// ---------------------------------------------------------------- RMSNorm + RoPE + relayout
__global__ __launch_bounds__(64) void norm_rope(const u16* __restrict__ qgk,
                                                const float* __restrict__ cosp,
                                                const float* __restrict__ sinp,
                                                const float* __restrict__ qw,
                                                const float* __restrict__ kw,
                                                u16* __restrict__ qf,
                                                u16* __restrict__ kf) {
    const int t = blockIdx.x;
    const int u = blockIdx.y;
    const int lane = threadIdx.x;
    const int b = t >> 11, s = t & 2047;
    const u16* src; const float* wgt; u16* dst;
    if (u < 16) {
        src = qgk + (long)t * 8704 + u * 512;
        wgt = qw;
        dst = qf + ((long)(b * 16 + u) * 2048 + s) * 256;
    } else {
        int kh = u - 16;
        src = qgk + (long)t * 8704 + 8192 + kh * 256;
        wgt = kw;
        dst = kf + ((long)(b * 2 + kh) * 2048 + s) * 256;
    }
    const int d0 = lane * 4;
    u16x4 raw = *(const u16x4*)(src + d0);
    float x0 = b2f(raw.x), x1 = b2f(raw.y), x2 = b2f(raw.z), x3 = b2f(raw.w);
    float ss = x0 * x0 + x1 * x1 + x2 * x2 + x3 * x3;
    for (int off = 32; off; off >>= 1) ss += __shfl_xor(ss, off, 64);
    float inv = rsqrtf(ss * (1.0f / 256.0f) + 1e-6f);
    float n0 = x0 * inv * wgt[d0 + 0];
    float n1 = x1 * inv * wgt[d0 + 1];
    float n2 = x2 * inv * wgt[d0 + 2];
    float n3 = x3 * inv * wgt[d0 + 3];
    float p0 = __shfl_xor(n0, 8, 64);
    float p1 = __shfl_xor(n1, 8, 64);
    float p2 = __shfl_xor(n2, 8, 64);
    float p3 = __shfl_xor(n3, 8, 64);
    if (lane < 16) {
        f32x4 c  = *(const f32x4*)(cosp + (long)t * 64 + d0);
        f32x4 sn = *(const f32x4*)(sinp + (long)t * 64 + d0);
        float sgn = (lane < 8) ? -1.f : 1.f;
        n0 = n0 * c[0] + sgn * p0 * sn[0];
        n1 = n1 * c[1] + sgn * p1 * sn[1];
        n2 = n2 * c[2] + sgn * p2 * sn[2];
        n3 = n3 * c[3] + sgn * p3 * sn[3];
    }
    const float qs = (u < 16) ? 0.0625f : 1.0f;
    n0 *= qs; n1 *= qs; n2 *= qs; n3 *= qs;
    u16x4 o;
    o.x = f2b(n0); o.y = f2b(n1); o.z = f2b(n2); o.w = f2b(n3);
    *(u16x4*)(dst + d0) = o;
}

// ---------------------------------------------------------------- flash attention + gate (v2)
// K/V staged via global_load_lds into XOR-swizzled linear LDS (swizzle applied on
// the global SOURCE address, rule #21). No staging registers, no staging ds_writes.
// Per tile: issue K glds then V glds; vmcnt(8)+barrier -> QK runs while V in flight;
// vmcnt(0)+barrier -> PV. LDS 72 KiB -> 2 blocks/CU. Swizzle rule everywhere:
// LDS slot chunk = logical_chunk ^ (row & 7), chunks are 16B.
__global__ __launch_bounds__(256) void attn_fused(const u16* __restrict__ qf,
                                                  const u16* __restrict__ kf,
                                                  const u16* __restrict__ vt,
                                                  const u16* __restrict__ qgk,
                                                  u16* __restrict__ attn_g) {
    __shared__ u16 Ks[64 * 256];   // [key][d]   row 512B, swizzled
    __shared__ u16 Vt[256 * 64];   // [d][key]   row 128B, swizzled
    __shared__ u16 P[64 * 64];     // [q][key]   row 128B, swizzled, wave-private rows
    const int flat = blockIdx.x;
    const int qt = 31 - (flat >> 5);   // LPT: heavy q-tiles first
    const int h  = flat & 15;
    const int b  = (flat >> 4) & 1;
    const int kh = h >> 3;             // GQA rep = 8
    const int tid = threadIdx.x;
    const int w = tid >> 6, lane = tid & 63;
    const int quad = lane >> 4, ml = lane & 15;
    const int qrow = qt * 64 + w * 16;

    const u16* qptr = qf + ((long)(b * 16 + h) * 2048 + qrow + ml) * 256;
    bf16x8 qfrag[8];
#pragma unroll
    for (int dd = 0; dd < 8; ++dd)
        qfrag[dd] = *(const bf16x8*)(qptr + dd * 32 + quad * 8);

    const f32x4 fz = {0.f, 0.f, 0.f, 0.f};
    f32x4 oacc[16];
#pragma unroll
    for (int i = 0; i < 16; ++i) oacc[i] = fz;
    float lsum[4] = {0.f, 0.f, 0.f, 0.f};

    const u16* kbp = kf + (long)(b * 2 + kh) * 2048 * 256;
    const u16* vbp = vt + (long)kh * 256 * 4096 + (long)b * 2048;

    // staging thread->slot mapping (LDS byte offset = tid*16 per issue, linear)
    const int krow = tid >> 5;               // K: 8 rows per issue
    const int kswz = (tid & 31) ^ krow;      // pre-swizzled source chunk
    const int vrow = tid >> 3;               // V: 32 d-rows per issue
    const int vswz = (tid & 7) ^ (vrow & 7);
    u16* ldsKw = &Ks[w * 512];               // wave-uniform dests (u16 units)
    u16* ldsVw = &Vt[w * 512];

    // compute-side swizzled chunk offsets (row&7 == ml&7 for all reads)
    const int m7 = ml & 7;

    const int nkt = qt + 1;  // causal: tiles 0..qt
    for (int kt = 0; kt < nkt; ++kt) {
        const int kb = kt * 64;
        __syncthreads();   // all waves done reading Ks/Vt of previous tile
#pragma unroll
        for (int i = 0; i < 8; ++i)
            glds16(kbp + (long)(kb + i * 8 + krow) * 256 + kswz * 8,
                   ldsKw + i * 2048);
#pragma unroll
        for (int i = 0; i < 8; ++i)
            glds16(vbp + (long)(i * 32 + vrow) * 4096 + kb + vswz * 8,
                   ldsVw + i * 2048);
        waitvm<8>();                        // own K loads done (V still in flight)
        __builtin_amdgcn_s_barrier();       // all waves' K done -> Ks readable
        __builtin_amdgcn_sched_barrier(0);

        // ---- S = Q K^T (pre-scaled q => sacc is the final score)
        f32x4 sacc[4];
#pragma unroll
        for (int i = 0; i < 4; ++i) sacc[i] = fz;
#pragma unroll
        for (int dd = 0; dd < 8; ++dd) {
            const int ck = (dd * 4 + quad) ^ m7;
            bf16x8 kf0 = *(const bf16x8*)&Ks[(0 * 16 + ml) * 256 + ck * 8];
            bf16x8 kf1 = *(const bf16x8*)&Ks[(1 * 16 + ml) * 256 + ck * 8];
            bf16x8 kf2 = *(const bf16x8*)&Ks[(2 * 16 + ml) * 256 + ck * 8];
            bf16x8 kf3 = *(const bf16x8*)&Ks[(3 * 16 + ml) * 256 + ck * 8];
            __builtin_amdgcn_s_setprio(1);
            sacc[0] = __builtin_amdgcn_mfma_f32_16x16x32_bf16(qfrag[dd], kf0, sacc[0], 0, 0, 0);
            sacc[1] = __builtin_amdgcn_mfma_f32_16x16x32_bf16(qfrag[dd], kf1, sacc[1], 0, 0, 0);
            sacc[2] = __builtin_amdgcn_mfma_f32_16x16x32_bf16(qfrag[dd], kf2, sacc[2], 0, 0, 0);
            sacc[3] = __builtin_amdgcn_mfma_f32_16x16x32_bf16(qfrag[dd], kf3, sacc[3], 0, 0, 0);
            __builtin_amdgcn_s_setprio(0);
        }

        // ---- fixed-shift softmax: p = exp(s - 16), no shuffles, no rescale
        const bool diag = (kt == qt);
#pragma unroll
        for (int nt = 0; nt < 4; ++nt)
#pragma unroll
            for (int r = 0; r < 4; ++r) {
                float sv = sacc[nt][r];
                const int row = w * 16 + quad * 4 + r;
                if (diag) {
                    int col = nt * 16 + ml;
                    sv = (col > (quad * 4 + r + w * 16)) ? -1e30f : sv;
                }
                float pv = __expf(sv - 16.0f);
                lsum[r] += pv;
                const int chk = (nt * 2 + (ml >> 3)) ^ ((quad * 4 + r) & 7);
                P[row * 64 + chk * 8 + m7] = f2b(pv);
            }

        waitvm<0>();                        // own V loads done
        __builtin_amdgcn_s_barrier();       // all waves' V done -> Vt readable
        __builtin_amdgcn_sched_barrier(0);

        // ---- O += P V   (P rows wave-private; lgkm deps ordered by compiler)
#pragma unroll
        for (int ks = 0; ks < 2; ++ks) {
            const int ck = (ks * 4 + quad) ^ m7;
            bf16x8 pfrag = *(const bf16x8*)&P[(w * 16 + ml) * 64 + ck * 8];
            __builtin_amdgcn_s_setprio(1);
#pragma unroll
            for (int dt = 0; dt < 16; ++dt) {
                bf16x8 vfrag = *(const bf16x8*)&Vt[(dt * 16 + ml) * 64 + ck * 8];
                oacc[dt] = __builtin_amdgcn_mfma_f32_16x16x32_bf16(pfrag, vfrag, oacc[dt], 0, 0, 0);
            }
            __builtin_amdgcn_s_setprio(0);
        }
    }

    // ---- single deferred row-sum reduction (16 lanes of each quad share a row)
#pragma unroll
    for (int off = 1; off < 16; off <<= 1)
#pragma unroll
        for (int r = 0; r < 4; ++r) lsum[r] += __shfl_xor(lsum[r], off, 64);

    // ---- epilogue: 1/l, sigmoid gate, store bf16 (4096 x 4096, col = h*256+d)
#pragma unroll
    for (int dt = 0; dt < 16; ++dt)
#pragma unroll
        for (int r = 0; r < 4; ++r) {
            int srow = qrow + quad * 4 + r;
            long tok = (long)b * 2048 + srow;
            int d = dt * 16 + ml;
            float o = oacc[dt][r] / lsum[r];
            float g = b2f(qgk[tok * 8704 + h * 512 + 256 + d]);
            float gv = o / (1.f + __expf(-g));
            attn_g[tok * 4096 + h * 256 + d] = f2b(gv);
        }
}

// ---------------------------------------------------------------- launch
extern "C" void kernel_launch(void* const* d_in, const int* in_sizes, int n_in,
                              void* d_out, int out_size, void* d_ws, size_t ws_size,
                              hipStream_t stream) {
    (void)in_sizes; (void)n_in; (void)out_size;
    const float* hidden = (const float*)d_in[0];
    const float* cosp   = (const float*)d_in[1];
    const float* sinp   = (const float*)d_in[2];
    const float* Wq     = (const float*)d_in[3];
    const float* Wk     = (const float*)d_in[4];
    const float* Wv     = (const float*)d_in[5];
    const float* Wo     = (const float*)d_in[6];
    const float* qw     = (const float*)d_in[7];
    const float* kw     = (const float*)d_in[8];
    float* out = (float*)d_out;

    char* p = (char*)d_ws;
    u16* h_bf   = (u16*)p; p += (size_t)8388608 * 2;   // hidden bf16 (4096x2048)
    u16* Wqk_bf = (u16*)p; p += (size_t)17825792 * 2;  // Wq||Wk (8704x2048)
    u16* Wv_bf  = (u16*)p; p += (size_t)1048576 * 2;   // Wv (512x2048)
    u16* Wo_bf  = (u16*)p; p += (size_t)8388608 * 2;   // Wo (2048x4096)
    u16* qgk    = (u16*)p; p += (size_t)35651584 * 2;  // (4096x8704)
    u16* v_t    = (u16*)p; p += (size_t)2097152 * 2;   // V^T (512x4096)
    u16* q_f    = (u16*)p; p += (size_t)16777216 * 2;  // (2,16,2048,256)
    u16* k_f    = (u16*)p; p += (size_t)2097152 * 2;   // (2,2,2048,256)
    u16* attn_g = (u16*)p; p += (size_t)16777216 * 2;  // (4096x4096)
    if ((size_t)(p - (char*)d_ws) > ws_size) return;

    cast_bf16<<<8192,  256, 0, stream>>>(hidden, h_bf, 8388608);
    cast_bf16<<<16384, 256, 0, stream>>>(Wq, Wqk_bf, 16777216);
    cast_bf16<<<1024,  256, 0, stream>>>(Wk, Wqk_bf + (size_t)8192 * 2048, 1048576);
    cast_bf16<<<1024,  256, 0, stream>>>(Wv, Wv_bf, 1048576);
    cast_bf16<<<8192,  256, 0, stream>>>(Wo, Wo_bf, 8388608);

    // qgk = hidden @ [Wq;Wk]^T   (4096 x 8704)
    gemm256<1, 256><<<dim3(544), 512, 0, stream>>>(h_bf, Wqk_bf, qgk, 4096, 8704, 2048, 34);
    // v_t = Wv @ hidden^T        (512 x 4096)
    gemm_bt<1><<<dim3(32, 4), 256, 0, stream>>>(Wv_bf, h_bf, v_t, 512, 4096, 2048);

    norm_rope<<<dim3(4096, 18), 64, 0, stream>>>(qgk, cosp, sinp, qw, kw, q_f, k_f);

    attn_fused<<<dim3(1024), 256, 0, stream>>>(q_f, k_f, v_t, qgk, attn_g);

    // out = attn_g @ Wo^T        (4096 x 2048) fp32
    gemm256<0, 128><<<dim3(256), 512, 0, stream>>>(attn_g, Wo_bf, out, 4096, 2048, 4096, 16);
}